// Round 6
// baseline (341.590 us; speedup 1.0000x reference)
//
#include <hip/hip_runtime.h>

// out[b, t, h] = sum_{j=0..4} x[b, t+j, h] * attn[b, t+j]
// B=32, H=768, LENGTH=2048, PADDED=2052, fp32 in/out. Memory-bound streaming.
//
// R6: the VANILLA cell of the cache-policy matrix — plain loads + plain
// stores. Measured matrix so far (kernel-only us):
//     nt+nt 108.5 | nt+plain 112 | cached+nt 125 | cached+plain = THIS.
// Rationale: m13's plain+plain float4 copy (also 1:1 R/W mixed) hits
// 6.29 TB/s and LN/RMSNorm (plain+plain) hit 82-86% of BW, while ALL our
// nt-involving cells sit at 3.4-3.95 TB/s, concurrency-independent.
// Theory: L2 is the HBM scheduler's smoothing buffer — plain stores batch
// dirty lines (1KB/wave store = 8 full 128B lines, write-allocate-no-fetch)
// and plain loads fill via MSHRs; nt on either stream bypasses L2 and the
// fine R/W interleave pays HBM bus-turnaround thrash. Bonus: plain loads let
// L3 retain x across iterations (R1/R3: FETCH 110 MB vs 227 MB of reads).
// ILP/occupancy exonerated (R2: 8-deep attempt, R4: 42% occ — all flat).

#define LEN     2048
#define WIDTH   5
#define PADDED  (LEN + WIDTH - 1)   // 2052
#define BATCH   32
#define HDIM    768
#define H4      (HDIM / 4)          // 192 float4 per row
#define TCHUNK  64
#define NCHUNK  (LEN / TCHUNK)      // 32

typedef float vfloat4 __attribute__((ext_vector_type(4)));

__global__ __launch_bounds__(256) void widthap_kernel(
    const vfloat4* __restrict__ x,
    const float*   __restrict__ attn,
    vfloat4*       __restrict__ out)
{
    const int tid  = blockIdx.x * blockDim.x + threadIdx.x;
    const int h4   = tid % H4;                                   // lane-contiguous
    const int rest = __builtin_amdgcn_readfirstlane(tid / H4);   // wave-uniform (192%64==0)
    const int b     = rest % BATCH;
    const int chunk = rest / BATCH;
    const int t0    = chunk * TCHUNK;

    const vfloat4* xp = x    + ((size_t)b * PADDED + t0) * H4 + h4;
    const float*   ap = attn +  (size_t)b * PADDED + t0;         // SGPR base -> s_load
    vfloat4*       op = out  + ((size_t)b * LEN    + t0) * H4 + h4;

    // ring of pre-weighted values w[j] = x[t0+j]*attn[t0+j]; each x read once
    vfloat4 w0, w1, w2, w3, w4;

    auto loadw = [&](int j) -> vfloat4 {
        const float   a = ap[j];              // scalar s_load (off vmcnt FIFO)
        const vfloat4 v = xp[(size_t)j * H4]; // PLAIN cached load
        return v * a;
    };

    w0 = loadw(0);
    w1 = loadw(1);
    w2 = loadw(2);
    w3 = loadw(3);

    #pragma unroll 8
    for (int i = 0; i < TCHUNK; ++i) {
        w4 = loadw(i + 4);
        const vfloat4 s = w0 + w1 + w2 + w3 + w4;
        op[(size_t)i * H4] = s;               // PLAIN store: L2 write-batching
        w0 = w1; w1 = w2; w2 = w3; w3 = w4;
    }
}

extern "C" void kernel_launch(void* const* d_in, const int* in_sizes, int n_in,
                              void* d_out, int out_size, void* d_ws, size_t ws_size,
                              hipStream_t stream) {
    const vfloat4* x    = (const vfloat4*)d_in[0];  // (32,1,2052,768) fp32
    const float*   attn = (const float*)d_in[1];    // (32,2052) fp32
    vfloat4*       out  = (vfloat4*)d_out;          // (32,1,2048,768) fp32

    const int total_threads = H4 * BATCH * NCHUNK;    // 196608
    const int block = 256;
    const int grid  = total_threads / block;          // 768 = 3 blocks/CU
    widthap_kernel<<<grid, block, 0, stream>>>(x, attn, out);
}